// Round 1
// baseline (356.122 us; speedup 1.0000x reference)
//
#include <hip/hip_runtime.h>
#include <cstdint>

#define HH 3000
#define WW 3000
#define CELLS (HH * WW)          // 9,000,000
#define TPB 256
#define CHUNK 16384              // cells per block in count/map passes
#define NBLK ((CELLS + CHUNK - 1) / CHUNK)   // 550
#define PER_THREAD (CHUNK / TPB)             // 64

// ws layout:
//   [0]  u32 nonzero-byte counter (detection)
//   [1]  u32 mode flag: 1 = activities is 1 byte/cell, 0 = 4 bytes/cell
//   +64  int blockSums[NBLK]
//   +4096 int map[CELLS]   (36 MB)  rank map: active -> index, inactive -> -1

__device__ __forceinline__ bool cell_active(const void* acts, int mode, int c) {
    if (mode) return ((const unsigned char*)acts)[c] != 0;
    return ((const unsigned int*)acts)[c] != 0u;
}

// Count nonzero BYTES in the first CELLS bytes (safe under either layout).
__global__ void k_detect(const uint4* __restrict__ acts, unsigned* cnt) {
    const int n16 = CELLS / 16;  // 562,500 (exact)
    int tid = blockIdx.x * blockDim.x + threadIdx.x;
    int stride = gridDim.x * blockDim.x;
    int c = 0;
    for (int idx = tid; idx < n16; idx += stride) {
        uint4 v = acts[idx];
        unsigned w0 = v.x, w1 = v.y, w2 = v.z, w3 = v.w;
        #pragma unroll
        for (int b = 0; b < 4; b++) {
            c += ((w0 >> (8 * b)) & 0xffu) != 0u;
            c += ((w1 >> (8 * b)) & 0xffu) != 0u;
            c += ((w2 >> (8 * b)) & 0xffu) != 0u;
            c += ((w3 >> (8 * b)) & 0xffu) != 0u;
        }
    }
    __shared__ int sm[TPB];
    sm[threadIdx.x] = c;
    __syncthreads();
    for (int off = TPB / 2; off > 0; off >>= 1) {
        if (threadIdx.x < off) sm[threadIdx.x] += sm[threadIdx.x + off];
        __syncthreads();
    }
    if (threadIdx.x == 0) atomicAdd(cnt, (unsigned)sm[0]);
}

__global__ void k_flag(unsigned* ws, int N) {
    if (threadIdx.x == 0 && blockIdx.x == 0)
        ws[1] = (ws[0] == (unsigned)N) ? 1u : 0u;
}

// Per-block active count over contiguous CHUNK cells.
__global__ void k_count(const void* __restrict__ acts, const unsigned* __restrict__ flagbuf,
                        int* __restrict__ blockSums) {
    const int mode = (int)flagbuf[1];
    const int t = threadIdx.x;
    const int base = blockIdx.x * CHUNK + t * PER_THREAD;
    int cnt = 0;
    #pragma unroll 8
    for (int s = 0; s < PER_THREAD; s++) {
        int c = base + s;
        if (c < CELLS) cnt += cell_active(acts, mode, c) ? 1 : 0;
    }
    __shared__ int sm[TPB];
    sm[t] = cnt;
    __syncthreads();
    for (int off = TPB / 2; off > 0; off >>= 1) {
        if (t < off) sm[t] += sm[t + off];
        __syncthreads();
    }
    if (t == 0) blockSums[blockIdx.x] = sm[0];
}

// Single-block exclusive scan of NBLK (=550) block sums.
__global__ void k_scan(int* __restrict__ blockSums) {
    __shared__ int sm[1024];
    int t = threadIdx.x;
    int v = (t < NBLK) ? blockSums[t] : 0;
    sm[t] = v;
    __syncthreads();
    for (int off = 1; off < 1024; off <<= 1) {
        int x = (t >= off) ? sm[t - off] : 0;
        __syncthreads();
        sm[t] += x;
        __syncthreads();
    }
    if (t < NBLK) blockSums[t] = sm[t] - v;  // exclusive
}

// Write rank map: active cell -> global active index, inactive -> -1.
__global__ void k_map(const void* __restrict__ acts, const unsigned* __restrict__ flagbuf,
                      const int* __restrict__ blockSums, int* __restrict__ map) {
    const int mode = (int)flagbuf[1];
    const int t = threadIdx.x;
    const int base = blockIdx.x * CHUNK + t * PER_THREAD;
    unsigned long long m = 0ull;
    #pragma unroll 8
    for (int s = 0; s < PER_THREAD; s++) {
        int c = base + s;
        if (c < CELLS && cell_active(acts, mode, c)) m |= (1ull << s);
    }
    int cnt = __popcll(m);
    __shared__ int sm[TPB];
    sm[t] = cnt;
    __syncthreads();
    for (int off = 1; off < TPB; off <<= 1) {
        int x = (t >= off) ? sm[t - off] : 0;
        __syncthreads();
        sm[t] += x;
        __syncthreads();
    }
    int rank = blockSums[blockIdx.x] + sm[t] - cnt;  // exclusive within grid
    for (int s = 0; s < PER_THREAD; s++) {
        int c = base + s;
        if (c < CELLS) {
            bool a = (m >> s) & 1ull;
            map[c] = a ? rank : -1;
            rank += a ? 1 : 0;
        }
    }
}

// One thread per cell: emit 4 neighbor entries for each active cell.
__global__ void k_emit(const int* __restrict__ map, const float* __restrict__ wts,
                       float* __restrict__ out, int N) {
    int c = blockIdx.x * blockDim.x + threadIdx.x;
    if (c >= CELLS) return;
    int n = map[c];
    if (n < 0) return;
    int i = c / WW;
    int j = c - i * WW;

    const int di[4] = {1, -1, 0, 0};
    const int dj[4] = {0, 0, 1, -1};
    float val[4], srcf[4], tgtf[4];
    #pragma unroll
    for (int k = 0; k < 4; k++) {
        int ni = i + di[k], nj = j + dj[k];
        bool inb = (unsigned)ni < (unsigned)HH && (unsigned)nj < (unsigned)WW;
        float v = 0.f, sf = 0.f, tf = 0.f;
        if (inb) {
            int nc = ni * WW + nj;
            int tn = map[nc];
            if (tn >= 0) {
                v = wts[nc];
                sf = (float)n;
                tf = (float)tn;
            }
        }
        val[k] = v; srcf[k] = sf; tgtf[k] = tf;
    }
    // vals: out[0 .. 4N), indices (as f32 pairs): out[4N .. 12N)
    float* vals = out;
    float* inds = out + (size_t)N * 4;
    *(float4*)(vals + (size_t)n * 4) = make_float4(val[0], val[1], val[2], val[3]);
    *(float4*)(inds + (size_t)n * 8)     = make_float4(srcf[0], tgtf[0], srcf[1], tgtf[1]);
    *(float4*)(inds + (size_t)n * 8 + 4) = make_float4(srcf[2], tgtf[2], srcf[3], tgtf[3]);
}

extern "C" void kernel_launch(void* const* d_in, const int* in_sizes, int n_in,
                              void* d_out, int out_size, void* d_ws, size_t ws_size,
                              hipStream_t stream) {
    const void* acts = d_in[0];
    const float* wts = (const float*)d_in[1];
    float* out = (float*)d_out;
    const int N = out_size / 12;  // vals N*4 + indices N*4*2

    unsigned* wsu = (unsigned*)d_ws;
    int* blockSums = (int*)((char*)d_ws + 64);
    int* map = (int*)((char*)d_ws + 4096);

    hipMemsetAsync(d_ws, 0, 64, stream);
    k_detect<<<1024, TPB, 0, stream>>>((const uint4*)acts, wsu);
    k_flag<<<1, 64, 0, stream>>>(wsu, N);
    k_count<<<NBLK, TPB, 0, stream>>>(acts, wsu, blockSums);
    k_scan<<<1, 1024, 0, stream>>>(blockSums);
    k_map<<<NBLK, TPB, 0, stream>>>(acts, wsu, blockSums, map);
    k_emit<<<(CELLS + TPB - 1) / TPB, TPB, 0, stream>>>(map, wts, out, N);
}

// Round 2
// 197.343 us; speedup vs baseline: 1.8046x; 1.8046x over previous
//
#include <hip/hip_runtime.h>
#include <cstdint>

#define HH 3000
#define WW 3000
#define CELLS (HH * WW)          // 9,000,000
#define TPB 256
#define WPR 48                   // 64-bit words per row (3000 bits -> 46.875, pad to 48)
#define NW (HH * WPR)            // 144,000 words
#define NBA ((NW + TPB - 1) / TPB)   // 563 blocks in build/prefix passes

typedef unsigned long long u64;

// ws layout:
//   [0]      u32 nonzero-byte counter (layout detection)
//   [4]      u32 mode flag: 1 = activities is 1 byte/cell, 0 = 4 bytes/cell
//   +64      int blockSums[NBA]
//   +4096            u64 bits[NW]   (1,152,000 B)  row-padded activity bitmask
//   +1,156,096       int wcnt[NW]   (576,000 B)    per-word popcounts
//   +1,732,096       int P[NW]      (576,000 B)    absolute exclusive prefix per word
#define BITS_OFF 4096
#define WCNT_OFF 1156096
#define P_OFF    1732096

// ---- layout detection: count nonzero bytes in first CELLS bytes (safe either way) ----
__global__ void k_detect(const uint4* __restrict__ acts, unsigned* cnt) {
    const int n16 = CELLS / 16;  // 562,500
    int tid = blockIdx.x * blockDim.x + threadIdx.x;
    int stride = gridDim.x * blockDim.x;
    int c = 0;
    for (int idx = tid; idx < n16; idx += stride) {
        uint4 v = acts[idx];
        #pragma unroll
        for (int b = 0; b < 4; b++) {
            c += ((v.x >> (8 * b)) & 0xffu) != 0u;
            c += ((v.y >> (8 * b)) & 0xffu) != 0u;
            c += ((v.z >> (8 * b)) & 0xffu) != 0u;
            c += ((v.w >> (8 * b)) & 0xffu) != 0u;
        }
    }
    __shared__ int sm[TPB];
    sm[threadIdx.x] = c;
    __syncthreads();
    for (int off = TPB / 2; off > 0; off >>= 1) {
        if (threadIdx.x < off) sm[threadIdx.x] += sm[threadIdx.x + off];
        __syncthreads();
    }
    if (threadIdx.x == 0) atomicAdd(cnt, (unsigned)sm[0]);
}

__global__ void k_flag(unsigned* ws, int N) {
    if (threadIdx.x == 0 && blockIdx.x == 0)
        ws[1] = (ws[0] == (unsigned)N) ? 1u : 0u;
}

// ---- build: one thread per 64-cell word; pack activity bits, count, block-reduce ----
__global__ void k_build(const void* __restrict__ acts, const unsigned* __restrict__ flagbuf,
                        u64* __restrict__ bits, int* __restrict__ wcnt,
                        int* __restrict__ blockSums) {
    const int mode = (int)flagbuf[1];
    const int w = blockIdx.x * TPB + threadIdx.x;
    u64 word = 0;
    if (w < NW) {
        int r = w / WPR;
        int wi = w - r * WPR;
        int nbits = WW - wi * 64;            // 64, 56 (wi=46), or <=0 (wi=47)
        if (nbits > 64) nbits = 64;
        if (nbits > 0) {
            long base = (long)r * WW + wi * 64;   // cell index; 8-aligned (3000%8==0)
            if (mode) {
                const u64* p = (const u64*)((const unsigned char*)acts + base);
                int n8 = nbits >> 3;               // 8 or 7
                for (int k = 0; k < n8; k++) {
                    u64 x = p[k];
                    u64 y = x | (x >> 4); y |= y >> 2; y |= y >> 1;
                    y &= 0x0101010101010101ull;                    // 1 in LSB of each nonzero byte
                    u64 m8 = (y * 0x0102040810204080ull) >> 56;    // pack byte-LSBs to 8 bits
                    word |= m8 << (k * 8);
                }
            } else {
                const uint4* p = (const uint4*)((const unsigned int*)acts + base);
                int n16 = nbits >> 2;              // 16 or 14
                for (int k = 0; k < n16; k++) {
                    uint4 v = p[k];
                    u64 m = (u64)(v.x != 0u) | ((u64)(v.y != 0u) << 1) |
                            ((u64)(v.z != 0u) << 2) | ((u64)(v.w != 0u) << 3);
                    word |= m << (k * 4);
                }
            }
        }
    }
    int cnt = __popcll(word);
    if (w < NW) { bits[w] = word; wcnt[w] = cnt; }
    __shared__ int sm[TPB];
    sm[threadIdx.x] = cnt;
    __syncthreads();
    for (int off = TPB / 2; off > 0; off >>= 1) {
        if (threadIdx.x < off) sm[threadIdx.x] += sm[threadIdx.x + off];
        __syncthreads();
    }
    if (threadIdx.x == 0) blockSums[blockIdx.x] = sm[0];
}

// ---- exclusive scan of NBA (=563) block sums, single block ----
__global__ void k_scan(int* __restrict__ blockSums) {
    __shared__ int sm[1024];
    int t = threadIdx.x;
    int v = (t < NBA) ? blockSums[t] : 0;
    sm[t] = v;
    __syncthreads();
    for (int off = 1; off < 1024; off <<= 1) {
        int x = (t >= off) ? sm[t - off] : 0;
        __syncthreads();
        sm[t] += x;
        __syncthreads();
    }
    if (t < NBA) blockSums[t] = sm[t] - v;  // exclusive
}

// ---- per-word absolute exclusive prefix P ----
__global__ void k_prefix(const int* __restrict__ wcnt, const int* __restrict__ blockSums,
                         int* __restrict__ P) {
    const int t = threadIdx.x;
    const int w = blockIdx.x * TPB + t;
    int v = (w < NW) ? wcnt[w] : 0;
    __shared__ int sm[TPB];
    sm[t] = v;
    __syncthreads();
    for (int off = 1; off < TPB; off <<= 1) {
        int x = (t >= off) ? sm[t - off] : 0;
        __syncthreads();
        sm[t] += x;
        __syncthreads();
    }
    if (w < NW) P[w] = blockSums[blockIdx.x] + sm[t] - v;  // absolute exclusive
}

// ---- emit: one thread per cell; aux (bits+P ~1.7MB) is L2-resident ----
__global__ void k_emit(const u64* __restrict__ bits, const int* __restrict__ P,
                       const float* __restrict__ wts, float* __restrict__ out, int N) {
    int c = blockIdx.x * blockDim.x + threadIdx.x;
    if (c >= CELLS) return;
    int i = c / WW;
    int j = c - i * WW;
    int wi = j >> 6, bit = j & 63;
    int w = i * WPR + wi;
    u64 mself = bits[w];
    if (!((mself >> bit) & 1ull)) return;
    int n = P[w] + __popcll(mself & ((1ull << bit) - 1ull));
    float nf = (float)n;

    float val[4], sf[4], tf[4];
    // neighbor order matches reference: (1,0), (-1,0), (0,1), (0,-1)
    { // down
        bool ok = (i < HH - 1);
        u64 wd = ok ? bits[w + WPR] : 0ull;
        bool act = ok && ((wd >> bit) & 1ull);
        val[0] = act ? wts[c + WW] : 0.f;
        sf[0]  = act ? nf : 0.f;
        tf[0]  = act ? (float)(P[w + WPR] + __popcll(wd & ((1ull << bit) - 1ull))) : 0.f;
    }
    { // up
        bool ok = (i > 0);
        u64 wd = ok ? bits[w - WPR] : 0ull;
        bool act = ok && ((wd >> bit) & 1ull);
        val[1] = act ? wts[c - WW] : 0.f;
        sf[1]  = act ? nf : 0.f;
        tf[1]  = act ? (float)(P[w - WPR] + __popcll(wd & ((1ull << bit) - 1ull))) : 0.f;
    }
    { // right
        bool ok = (j < WW - 1);
        int wn = (bit < 63) ? w : w + 1;
        int b2 = (bit < 63) ? bit + 1 : 0;
        u64 wd = ok ? ((bit < 63) ? mself : bits[wn]) : 0ull;
        bool act = ok && ((wd >> b2) & 1ull);
        val[2] = act ? wts[c + 1] : 0.f;
        sf[2]  = act ? nf : 0.f;
        tf[2]  = act ? (float)(P[wn] + __popcll(wd & ((1ull << b2) - 1ull))) : 0.f;
    }
    { // left
        bool ok = (j > 0);
        int wn = (bit > 0) ? w : w - 1;
        int b2 = (bit > 0) ? bit - 1 : 63;
        u64 wd = ok ? ((bit > 0) ? mself : bits[wn]) : 0ull;
        bool act = ok && ((wd >> b2) & 1ull);
        val[3] = act ? wts[c - 1] : 0.f;
        sf[3]  = act ? nf : 0.f;
        tf[3]  = act ? (float)(P[wn] + __popcll(wd & ((1ull << b2) - 1ull))) : 0.f;
    }

    float* vals = out;
    float* inds = out + (size_t)N * 4;
    *(float4*)(vals + (size_t)n * 4)     = make_float4(val[0], val[1], val[2], val[3]);
    *(float4*)(inds + (size_t)n * 8)     = make_float4(sf[0], tf[0], sf[1], tf[1]);
    *(float4*)(inds + (size_t)n * 8 + 4) = make_float4(sf[2], tf[2], sf[3], tf[3]);
}

extern "C" void kernel_launch(void* const* d_in, const int* in_sizes, int n_in,
                              void* d_out, int out_size, void* d_ws, size_t ws_size,
                              hipStream_t stream) {
    const void* acts = d_in[0];
    const float* wts = (const float*)d_in[1];
    float* out = (float*)d_out;
    const int N = out_size / 12;  // vals N*4 + indices N*4*2

    unsigned* wsu = (unsigned*)d_ws;
    int* blockSums = (int*)((char*)d_ws + 64);
    u64* bits = (u64*)((char*)d_ws + BITS_OFF);
    int* wcnt = (int*)((char*)d_ws + WCNT_OFF);
    int* P    = (int*)((char*)d_ws + P_OFF);

    hipMemsetAsync(d_ws, 0, 64, stream);
    k_detect<<<1024, TPB, 0, stream>>>((const uint4*)acts, wsu);
    k_flag<<<1, 64, 0, stream>>>(wsu, N);
    k_build<<<NBA, TPB, 0, stream>>>(acts, wsu, bits, wcnt, blockSums);
    k_scan<<<1, 1024, 0, stream>>>(blockSums);
    k_prefix<<<NBA, TPB, 0, stream>>>(wcnt, blockSums, P);
    k_emit<<<(CELLS + TPB - 1) / TPB, TPB, 0, stream>>>(bits, P, wts, out, N);
}

// Round 3
// 176.282 us; speedup vs baseline: 2.0202x; 1.1195x over previous
//
#include <hip/hip_runtime.h>
#include <cstdint>

#define HH 3000
#define WW 3000
#define CELLS (HH * WW)          // 9,000,000
#define WPR 48                   // 64-bit words per row (3000 bits, padded)
#define NW (HH * WPR)            // 144,000 words

typedef unsigned long long u64;

// ws layout (all regions fully written before read; no memset needed):
//   +0        int detectPartial[1024]   (4096 B)
//   +4096     u32 mode                  (1 = byte/cell, 0 = 4B/cell)
//   +4160     int rowSums[3000]         -> exclusive row prefix after scan
//   +16384    u64 bits[NW]              (1,152,000 B)
//   +1168384  int wcnt[NW]              (576,000 B)
//   +1744384  int P[NW]                 (576,000 B) absolute exclusive prefix per word
#define DET_OFF  0
#define MODE_OFF 4096
#define ROW_OFF  4160
#define BITS_OFF 16384
#define WCNT_OFF 1168384
#define P_OFF    1744384

__device__ __forceinline__ unsigned nzbytes(unsigned x) {
    unsigned y = x | (x >> 4); y |= y >> 2; y |= y >> 1;
    return __popc(y & 0x01010101u);
}

// ---- detect: count nonzero bytes in first CELLS bytes (valid under either layout) ----
__global__ void k_detect(const uint4* __restrict__ acts, int* __restrict__ partial) {
    const int n16 = CELLS / 16;  // 562,500
    int tid = blockIdx.x * 256 + threadIdx.x;
    int c = 0;
    for (int idx = tid; idx < n16; idx += 1024 * 256) {
        uint4 v = acts[idx];
        c += nzbytes(v.x) + nzbytes(v.y) + nzbytes(v.z) + nzbytes(v.w);
    }
    __shared__ int sm[256];
    sm[threadIdx.x] = c;
    __syncthreads();
    for (int off = 128; off > 0; off >>= 1) {
        if (threadIdx.x < off) sm[threadIdx.x] += sm[threadIdx.x + off];
        __syncthreads();
    }
    if (threadIdx.x == 0) partial[blockIdx.x] = sm[0];
}

__global__ void k_flag(const int* __restrict__ partial, unsigned* __restrict__ modep, int N) {
    __shared__ int sm[1024];
    int t = threadIdx.x;
    sm[t] = partial[t];
    __syncthreads();
    for (int off = 512; off > 0; off >>= 1) {
        if (t < off) sm[t] += sm[t + off];
        __syncthreads();
    }
    if (t == 0) *modep = (sm[0] == N) ? 1u : 0u;
}

// ---- build: one wave per 64-bit word via ballot; one block per row ----
__global__ void k_build(const void* __restrict__ acts, const unsigned* __restrict__ modep,
                        u64* __restrict__ bits, int* __restrict__ wcnt,
                        int* __restrict__ rowSums) {
    const int mode = (int)*modep;
    const int r = blockIdx.x;
    const int lane = threadIdx.x & 63;
    const int wv = threadIdx.x >> 6;
    const long rowbase = (long)r * WW;
    int mycnt = 0;
    for (int it = 0; it < 12; ++it) {
        int wi = it * 4 + wv;           // 0..47
        int j = wi * 64 + lane;
        bool a = false;
        if (j < WW) {
            if (mode) a = ((const unsigned char*)acts)[rowbase + j] != 0;
            else      a = ((const unsigned*)acts)[rowbase + j] != 0u;
        }
        u64 m = __ballot(a);
        if (lane == 0) {
            int w = r * WPR + wi;
            bits[w] = m;
            int pc = __popcll(m);
            wcnt[w] = pc;
            mycnt += pc;
        }
    }
    __shared__ int sm[4];
    if (lane == 0) sm[wv] = mycnt;
    __syncthreads();
    if (threadIdx.x == 0) rowSums[r] = sm[0] + sm[1] + sm[2] + sm[3];
}

// ---- exclusive scan of 3000 row sums, single block, 3 chunks with carry ----
__global__ void k_scanrows(int* __restrict__ rowSums) {
    __shared__ int sm[1024];
    int t = threadIdx.x;
    int carry = 0;
    for (int chunk = 0; chunk < 3; ++chunk) {
        int idx = chunk * 1024 + t;
        int v = (idx < HH) ? rowSums[idx] : 0;
        sm[t] = v;
        __syncthreads();
        for (int off = 1; off < 1024; off <<= 1) {
            int x = (t >= off) ? sm[t - off] : 0;
            __syncthreads();
            sm[t] += x;
            __syncthreads();
        }
        if (idx < HH) rowSums[idx] = carry + sm[t] - v;  // exclusive
        int total = sm[1023];
        __syncthreads();
        carry += total;
    }
}

// ---- per-word absolute prefix: one wave per row (48 words), wave shfl-scan ----
__global__ void k_prefix(const int* __restrict__ wcnt, const int* __restrict__ rowPrefix,
                         int* __restrict__ P) {
    const int lane = threadIdx.x & 63;
    const int wv = threadIdx.x >> 6;
    const int r = blockIdx.x * 4 + wv;
    if (r >= HH) return;
    const int w = r * WPR + lane;
    int v = (lane < WPR) ? wcnt[w] : 0;
    int x = v;
    #pragma unroll
    for (int off = 1; off < 64; off <<= 1) {
        int y = __shfl_up(x, off);
        if (lane >= off) x += y;
    }
    if (lane < WPR) P[w] = rowPrefix[r] + (x - v);  // exclusive within row + row base
}

// ---- emit: grid (12, 3000); LDS-staged, fully-coalesced wave stores ----
__global__ __launch_bounds__(256) void k_emit(const u64* __restrict__ bits,
                                              const int* __restrict__ P,
                                              const float* __restrict__ wts,
                                              float* __restrict__ out, int N) {
    const int t = threadIdx.x;
    const int lane = t & 63;
    const int wv = t >> 6;
    const int i = blockIdx.y;
    const int j0 = blockIdx.x * 256 + t;

    __shared__ float4 s_vals[4][64];
    __shared__ float4 s_inds[4][128];

    bool inrow = (j0 < WW);
    int j = inrow ? j0 : (WW - 1);
    int wi = j >> 6, bit = j & 63;
    int w = i * WPR + wi;
    u64 mself = bits[w];
    bool cellact = (mself >> bit) & 1ull;
    int v = P[w] + __popcll(mself & ((1ull << bit) - 1ull));  // virtual rank
    bool act = inrow && cellact;
    if (!inrow && cellact) v += 1;   // keep v monotonic past row end

    int n0 = __shfl(v, 0);                       // wave base rank
    int a  = __shfl(v + (act ? 1 : 0), 63) - n0; // active lanes in wave

    if (act) {
        float nf = (float)v;
        const long c = (long)i * WW + j;
        float val[4], sf[4], tf[4];
        { // (1,0) down
            bool ok = (i < HH - 1);
            u64 wd = ok ? bits[w + WPR] : 0ull;
            bool aa = ok && ((wd >> bit) & 1ull);
            val[0] = aa ? wts[c + WW] : 0.f; sf[0] = aa ? nf : 0.f;
            tf[0] = aa ? (float)(P[w + WPR] + __popcll(wd & ((1ull << bit) - 1ull))) : 0.f;
        }
        { // (-1,0) up
            bool ok = (i > 0);
            u64 wd = ok ? bits[w - WPR] : 0ull;
            bool aa = ok && ((wd >> bit) & 1ull);
            val[1] = aa ? wts[c - WW] : 0.f; sf[1] = aa ? nf : 0.f;
            tf[1] = aa ? (float)(P[w - WPR] + __popcll(wd & ((1ull << bit) - 1ull))) : 0.f;
        }
        { // (0,1) right
            bool ok = (j < WW - 1);
            int wn = (bit < 63) ? w : w + 1;
            int b2 = (bit < 63) ? bit + 1 : 0;
            u64 wd = ok ? ((bit < 63) ? mself : bits[wn]) : 0ull;
            bool aa = ok && ((wd >> b2) & 1ull);
            val[2] = aa ? wts[c + 1] : 0.f; sf[2] = aa ? nf : 0.f;
            tf[2] = aa ? (float)(P[wn] + __popcll(wd & ((1ull << b2) - 1ull))) : 0.f;
        }
        { // (0,-1) left
            bool ok = (j > 0);
            int wn = (bit > 0) ? w : w - 1;
            int b2 = (bit > 0) ? bit - 1 : 63;
            u64 wd = ok ? ((bit > 0) ? mself : bits[wn]) : 0ull;
            bool aa = ok && ((wd >> b2) & 1ull);
            val[3] = aa ? wts[c - 1] : 0.f; sf[3] = aa ? nf : 0.f;
            tf[3] = aa ? (float)(P[wn] + __popcll(wd & ((1ull << b2) - 1ull))) : 0.f;
        }
        int rloc = v - n0;
        s_vals[wv][rloc]        = make_float4(val[0], val[1], val[2], val[3]);
        s_inds[wv][2 * rloc]     = make_float4(sf[0], tf[0], sf[1], tf[1]);
        s_inds[wv][2 * rloc + 1] = make_float4(sf[2], tf[2], sf[3], tf[3]);
    }
    __syncthreads();

    float4* valsg = (float4*)out;                     // N float4s
    float4* indsg = (float4*)(out + (size_t)N * 4);   // 2N float4s
    if (lane < a) valsg[(size_t)n0 + lane] = s_vals[wv][lane];
    int twoa = 2 * a;
    if (lane < twoa)      indsg[2 * (size_t)n0 + lane]      = s_inds[wv][lane];
    if (lane + 64 < twoa) indsg[2 * (size_t)n0 + 64 + lane] = s_inds[wv][lane + 64];
}

extern "C" void kernel_launch(void* const* d_in, const int* in_sizes, int n_in,
                              void* d_out, int out_size, void* d_ws, size_t ws_size,
                              hipStream_t stream) {
    const void* acts = d_in[0];
    const float* wts = (const float*)d_in[1];
    float* out = (float*)d_out;
    const int N = out_size / 12;

    int* det       = (int*)((char*)d_ws + DET_OFF);
    unsigned* modep = (unsigned*)((char*)d_ws + MODE_OFF);
    int* rows      = (int*)((char*)d_ws + ROW_OFF);
    u64* bits      = (u64*)((char*)d_ws + BITS_OFF);
    int* wcnt      = (int*)((char*)d_ws + WCNT_OFF);
    int* P         = (int*)((char*)d_ws + P_OFF);

    k_detect<<<1024, 256, 0, stream>>>((const uint4*)acts, det);
    k_flag<<<1, 1024, 0, stream>>>(det, modep, N);
    k_build<<<HH, 256, 0, stream>>>(acts, modep, bits, wcnt, rows);
    k_scanrows<<<1, 1024, 0, stream>>>(rows);
    k_prefix<<<(HH + 3) / 4, 256, 0, stream>>>(wcnt, rows, P);
    k_emit<<<dim3(12, HH), 256, 0, stream>>>(bits, P, wts, out, N);
}